// Round 9
// baseline (6940.438 us; speedup 1.0000x reference)
//
#include <hip/hip_runtime.h>
#include <math.h>

#define Bz 32
#define Lz 2048
#define Iz 64
#define Hz 512
#define HALFz 256
#define DTz 0.05f
#define NMEM 8
#define NPAIR 16
#define TPB 512

typedef unsigned long long u64;

__device__ __forceinline__ bool tagok(u64 v, unsigned tag) {
  u64 want = (u64)tag | ((u64)tag << 48);
  return ((v ^ want) & 0xFFFF00000000FFFFull) == 0ull;
}
__device__ __forceinline__ u64 packv(float f, unsigned tag) {
  return (u64)tag | ((u64)__float_as_uint(f) << 16) | ((u64)tag << 48);
}
__device__ __forceinline__ float unpackv(u64 v) {
  return __uint_as_float((unsigned)(v >> 16));
}

// sc0-only global access (bypass L1, stay at device-coherent point).
__device__ __forceinline__ u64 load_sc0(const u64* p) {
  u64 r;
  asm volatile("global_load_dwordx2 %0, %1, off sc0\n\t"
               "s_waitcnt vmcnt(0)"
               : "=&v"(r) : "v"(p) : "memory");
  return r;
}
__device__ __forceinline__ void store_sc0(u64* p, u64 v) {
  asm volatile("global_store_dwordx2 %0, %1, off sc0"
               :: "v"(p), "v"(v) : "memory");
}

// ============== dual-chain latency-hiding cooperative kernel ==============
// R8 measured: exchange RTT ~MALL (~600-900cy) is a floor (sc0 didn't make
// polls L2-local; FETCH unchanged). So HIDE it: each block serves TWO batch
// chains (A=2p, B=2p+1) with the SAME 64-column slice -> weights shared in
// registers. blockIdx = m*16+p (members of a pair differ by 16 -> same mod-8
// residue -> same XCD under round-robin; perf-only, Y-path covers the rest).
// Per step: compute A, publish A, compute B (hides A's RTT), publish B,
// issue A-poll (A published ~750cy ago -> hit), RFF A, validate A, issue
// B-poll, RFF B, validate B, barrier. Exchange = tagged u64 (torn-write-safe)
// dual-published to X (sc0) and Y (agent atomic, MALL) as in R6/R8; parity-2
// buffer reuse is barrier-ordered (publish(t+2) happens after poll(t+1)).
// NOTE (R5 bug): rff_acc's shfl chain fully reduces wx into every lane of the
// 16-lane kseg group -> zc/zs complete per-lane; never re-reduce.
__global__ __launch_bounds__(TPB, 1) void coesn_2c(
    const float* __restrict__ x, const float* __restrict__ x2h,
    const float* __restrict__ h2h, const float* __restrict__ bias,
    const float* __restrict__ gam, const float* __restrict__ eps,
    const float* __restrict__ W_rff, u64* __restrict__ Xb,
    u64* __restrict__ Yb, float* __restrict__ out) {
  __shared__ __align__(16) float hyfA[2][Hz];
  __shared__ __align__(16) float hyfB[2][Hz];
  __shared__ __align__(16) float xbA[2][Iz];
  __shared__ __align__(16) float xbB[2][Iz];

  const int p  = blockIdx.x & 15;     // pair id
  const int m  = blockIdx.x >> 4;     // member id (column slice)
  const int bA = 2 * p, bB = 2 * p + 1;
  const int u  = threadIdx.x;
  const int w  = u >> 6;
  const int l  = u & 63;
  const int c0 = m * 64;
  const int j  = ((l & 1) << 2) | (l & 2) | ((l >> 2) & 1);  // fold col map
  const int mycol = c0 + w * 8 + j;
  const int rloc = u >> 4, kseg = u & 15;

  // ---- weights into registers (shared by both chains) ----
  float wreg[8][8];   // h2h[8l+r][c0+8w+c]
  {
    const float* hrow = h2h + (size_t)(8 * l) * Hz + c0 + 8 * w;
    #pragma unroll
    for (int r = 0; r < 8; ++r) {
      float4 v0 = *(const float4*)(hrow + (size_t)r * Hz);
      float4 v1 = *(const float4*)(hrow + (size_t)r * Hz + 4);
      wreg[r][0] = v0.x; wreg[r][1] = v0.y; wreg[r][2] = v0.z; wreg[r][3] = v0.w;
      wreg[r][4] = v1.x; wreg[r][5] = v1.y; wreg[r][6] = v1.z; wreg[r][7] = v1.w;
    }
  }
  float xreg[8];      // x2h[l][c0+8w+c]
  {
    float4 v0 = *(const float4*)(x2h + (size_t)l * Hz + c0 + 8 * w);
    float4 v1 = *(const float4*)(x2h + (size_t)l * Hz + c0 + 8 * w + 4);
    xreg[0] = v0.x; xreg[1] = v0.y; xreg[2] = v0.z; xreg[3] = v0.w;
    xreg[4] = v1.x; xreg[5] = v1.y; xreg[6] = v1.z; xreg[7] = v1.w;
  }
  float wr[32];       // W_rff[m*32+rloc][kseg*32 ..)
  {
    const float* wp = W_rff + (size_t)(m * 32 + rloc) * Hz + kseg * 32;
    #pragma unroll
    for (int i = 0; i < 32; ++i) wr[i] = wp[i];
  }

  const float bu = bias[mycol];
  const float gu = gam[mycol];
  const float eu = eps[mycol];
  float hyA = 0.f, hzA = 0.f, zcA = 0.f, zsA = 0.f;
  float hyB = 0.f, hzB = 0.f, zcB = 0.f, zsB = 0.f;
  hyfA[0][u] = 0.f; hyfB[0][u] = 0.f;
  if (u < 16) ((float4*)xbA[0])[u] = ((const float4*)(x + (size_t)bA * Lz * Iz))[u];
  else if (u >= 64 && u < 80)
    ((float4*)xbB[0])[u - 64] = ((const float4*)(x + (size_t)bB * Lz * Iz))[u - 64];
  __syncthreads();

  // matvec + 10-shuffle fold for one chain; returns full sum for col j(l)
  auto matvec = [&](const float* hcur, const float* xcur) -> float {
    float hv[8];
    {
      const float4* hp = (const float4*)hcur;
      int q0 = 2 * l, q1 = 2 * l + 1;
      float4 h0 = hp[q0 ^ ((q0 >> 3) & 7)];
      float4 h1 = hp[q1 ^ ((q1 >> 3) & 7)];
      hv[0] = h0.x; hv[1] = h0.y; hv[2] = h0.z; hv[3] = h0.w;
      hv[4] = h1.x; hv[5] = h1.y; hv[6] = h1.z; hv[7] = h1.w;
    }
    float a[8] = {0.f,0.f,0.f,0.f,0.f,0.f,0.f,0.f};
    #pragma unroll
    for (int r = 0; r < 8; ++r) {
      float h = hv[r];
      #pragma unroll
      for (int c = 0; c < 8; ++c) a[c] = fmaf(h, wreg[r][c], a[c]);
    }
    {
      float xv = xcur[l];
      #pragma unroll
      for (int c = 0; c < 8; ++c) a[c] = fmaf(xv, xreg[c], a[c]);
    }
    #pragma unroll
    for (int i = 0; i < 4; ++i) {
      float snd = (l & 1) ? a[i] : a[i + 4];
      float rcv = __shfl_xor(snd, 1);
      a[i] = ((l & 1) ? a[i + 4] : a[i]) + rcv;
    }
    #pragma unroll
    for (int i = 0; i < 2; ++i) {
      float snd = (l & 2) ? a[i] : a[i + 2];
      float rcv = __shfl_xor(snd, 2);
      a[i] = ((l & 2) ? a[i + 2] : a[i]) + rcv;
    }
    float s;
    {
      float snd = (l & 4) ? a[0] : a[1];
      float rcv = __shfl_xor(snd, 4);
      s = ((l & 4) ? a[1] : a[0]) + rcv;
    }
    s += __shfl_xor(s, 8); s += __shfl_xor(s, 16); s += __shfl_xor(s, 32);
    return s;
  };

  auto update = [&](float s, float& hy, float& hz) {
    s += bu;
    float e2 = __expf(s + s);
    float pre = 1.f - 2.f * __builtin_amdgcn_rcpf(e2 + 1.f);   // fast tanh
    float hzn = fmaf(DTz, pre - gu * hy - eu * hz, hz);
    hy = fmaf(DTz, hzn, hy);
    hz = hzn;
  };

  auto rff_acc = [&](const float* hsrc, float& zc, float& zs) {
    float acc = 0.f;
    const float4* hp = (const float4*)hsrc;
    #pragma unroll
    for (int i = 0; i < 8; ++i) {
      int q = kseg * 8 + i;
      float4 h4 = hp[q ^ ((q >> 3) & 7)];
      acc = fmaf(h4.x, wr[4 * i], acc);
      acc = fmaf(h4.y, wr[4 * i + 1], acc);
      acc = fmaf(h4.z, wr[4 * i + 2], acc);
      acc = fmaf(h4.w, wr[4 * i + 3], acc);
    }
    acc += __shfl_xor(acc, 1); acc += __shfl_xor(acc, 2);
    acc += __shfl_xor(acc, 4); acc += __shfl_xor(acc, 8);
    float sv, cv;
    __sincosf(acc, &sv, &cv);
    zc += cv; zs += sv;   // complete per-lane across the 16-lane group
  };

  auto validate = [&](u64 spec, u64* XA, u64* YA, unsigned tag,
                      float (*hyf)[Hz], int nxt) {
    u64 v = spec;
    if (!tagok(v, tag)) {
      int it = 0;
      for (;;) {
        v = load_sc0(XA + u);
        if (tagok(v, tag)) break;
        if (it >= 2) {
          v = __hip_atomic_load(YA + u, __ATOMIC_RELAXED,
                                __HIP_MEMORY_SCOPE_AGENT);
          if (tagok(v, tag)) break;
        }
        if (++it > (1 << 20)) break;   // safety bail
      }
    }
    int q = u >> 2;
    hyf[nxt][((q ^ ((q >> 3) & 7)) << 2) | (u & 3)] = unpackv(v);
  };

  for (int t = 0; t < Lz; ++t) {
    const int cur = t & 1, nxt = cur ^ 1;
    const unsigned tag = (unsigned)(t + 1);
    u64* XAa = Xb + ((size_t)nxt * Bz + bA) * Hz;
    u64* YAa = Yb + ((size_t)nxt * Bz + bA) * Hz;
    u64* XAb = Xb + ((size_t)nxt * Bz + bB) * Hz;
    u64* YAb = Yb + ((size_t)nxt * Bz + bB) * Hz;

    // ---- x(t+1) prefetch (wave0 -> A, wave1 -> B) ----
    if (t + 1 < Lz) {
      if (u < 16)
        ((float4*)xbA[nxt])[u] = ((const float4*)(x + ((size_t)bA * Lz + t + 1) * Iz))[u];
      else if (u >= 64 && u < 80)
        ((float4*)xbB[nxt])[u - 64] = ((const float4*)(x + ((size_t)bB * Lz + t + 1) * Iz))[u - 64];
    }

    // ---- chain A: compute + publish ----
    {
      float s = matvec(hyfA[cur], xbA[cur]);
      update(s, hyA, hzA);
      if (l < 8) {
        u64 pv = packv(hyA, tag);
        store_sc0(XAa + mycol, pv);
        __hip_atomic_store(YAa + mycol, pv, __ATOMIC_RELAXED,
                           __HIP_MEMORY_SCOPE_AGENT);
        int q = mycol >> 2;
        hyfA[nxt][((q ^ ((q >> 3) & 7)) << 2) | (mycol & 3)] = hyA;
      }
    }

    // ---- chain B: compute + publish (hides A's exchange RTT) ----
    {
      float s = matvec(hyfB[cur], xbB[cur]);
      update(s, hyB, hzB);
      if (l < 8) {
        u64 pv = packv(hyB, tag);
        store_sc0(XAb + mycol, pv);
        __hip_atomic_store(YAb + mycol, pv, __ATOMIC_RELAXED,
                           __HIP_MEMORY_SCOPE_AGENT);
        int q = mycol >> 2;
        hyfB[nxt][((q ^ ((q >> 3) & 7)) << 2) | (mycol & 3)] = hyB;
      }
    }

    // ---- speculative A-poll (A was published a full compute phase ago) ----
    u64 specA = 0;
    if (w != m)
      asm volatile("global_load_dwordx2 %0, %1, off sc0"
                   : "=&v"(specA) : "v"(XAa + u) : "memory");

    // ---- RFF A in the shadow ----
    if (t > 0) rff_acc(hyfA[cur], zcA, zsA);

    // ---- validate A ----
    if (w != m) {
      asm volatile("s_waitcnt vmcnt(0)" : "+v"(specA) :: "memory");
      validate(specA, XAa, YAa, tag, hyfA, nxt);
    }

    // ---- speculative B-poll ----
    u64 specB = 0;
    if (w != m)
      asm volatile("global_load_dwordx2 %0, %1, off sc0"
                   : "=&v"(specB) : "v"(XAb + u) : "memory");

    // ---- RFF B in the shadow ----
    if (t > 0) rff_acc(hyfB[cur], zcB, zsB);

    // ---- validate B ----
    if (w != m) {
      asm volatile("s_waitcnt vmcnt(0)" : "+v"(specB) :: "memory");
      validate(specB, XAb, YAb, tag, hyfB, nxt);
    }
    __syncthreads();
  }

  // final RFF terms on hy(Lz) (loop covered hy(1)..hy(Lz-1)); Lz even -> [0]
  rff_acc(hyfA[0], zcA, zsA);
  rff_acc(hyfB[0], zcB, zsB);

  if (l < 8) {
    out[(size_t)Bz * Hz + (size_t)bA * Hz + mycol] = hyA;
    out[(size_t)Bz * Hz + (size_t)bB * Hz + mycol] = hyB;
  }
  if (kseg == 0) {
    const float sc = 0.0625f / 2048.f;   // (1/sqrt(256)) / L
    out[(size_t)bA * Hz + m * 32 + rloc] = zcA * sc;
    out[(size_t)bA * Hz + HALFz + m * 32 + rloc] = zsA * sc;
    out[(size_t)bB * Hz + m * 32 + rloc] = zcB * sc;
    out[(size_t)bB * Hz + HALFz + m * 32 + rloc] = zsB * sc;
  }
}

// ================= single-block-per-batch fallback (proven R1) =================
#define FMA4(P, S, W) do { (P).x = fmaf((S), (W).x, (P).x); (P).y = fmaf((S), (W).y, (P).y); \
                           (P).z = fmaf((S), (W).z, (P).z); (P).w = fmaf((S), (W).w, (P).w); } while(0)

__global__ __launch_bounds__(512) void coesn_scan_fb(
    const float* __restrict__ x, const float* __restrict__ x2h,
    const float* __restrict__ h2h, const float* __restrict__ bias,
    const float* __restrict__ gam, const float* __restrict__ eps,
    const float* __restrict__ W_rff, float* __restrict__ out) {
  const int b = blockIdx.x;
  const int u = threadIdx.x;
  __shared__ __align__(16) float hy_lds[Hz];
  __shared__ __align__(16) float x_lds[Iz];
  __shared__ float4 part[4][128];
  __shared__ float wx_lds[HALFz];

  float hy = 0.f, hz = 0.f, zsum = 0.f;
  const float bu = bias[u];
  const float gu = gam[u];
  const float eu = eps[u];

  const int kq = u >> 7;
  const int g  = u & 127;
  const int jj = u >> 2;
  const int ks = u & 3;

  const float4* __restrict__ H4 = (const float4*)h2h;
  const float4* __restrict__ X2 = (const float4*)x2h;
  const float4* __restrict__ W4 = (const float4*)W_rff;
  const float4* __restrict__ XG = (const float4*)x;
  const float4* hy4 = (const float4*)hy_lds;

  hy_lds[u] = 0.f;
  if (u < 16) ((float4*)x_lds)[u] = XG[(long)b * Lz * 16 + u];
  __syncthreads();

  for (int t = 0; t < Lz; ++t) {
    float4 p = make_float4(0.f, 0.f, 0.f, 0.f);
    {
      const float4* hp = (const float4*)&hy_lds[kq << 7];
      #pragma unroll 8
      for (int k4 = 0; k4 < 32; ++k4) {
        float4 hv = hp[k4];
        const float4* wr2 = &H4[(size_t)((kq << 7) + (k4 << 2)) * 128 + g];
        float4 w0 = wr2[0]; float4 w1 = wr2[128]; float4 w2 = wr2[256]; float4 w3 = wr2[384];
        FMA4(p, hv.x, w0); FMA4(p, hv.y, w1); FMA4(p, hv.z, w2); FMA4(p, hv.w, w3);
      }
      const float4* xp = (const float4*)&x_lds[kq << 4];
      #pragma unroll
      for (int k4 = 0; k4 < 4; ++k4) {
        float4 xv = xp[k4];
        const float4* wr2 = &X2[(size_t)((kq << 4) + (k4 << 2)) * 128 + g];
        float4 w0 = wr2[0]; float4 w1 = wr2[128]; float4 w2 = wr2[256]; float4 w3 = wr2[384];
        FMA4(p, xv.x, w0); FMA4(p, xv.y, w1); FMA4(p, xv.z, w2); FMA4(p, xv.w, w3);
      }
    }
    part[kq][g] = p;
    __syncthreads();
    {
      const float* pp = (const float*)part;
      float s = (pp[u] + pp[512 + u]) + (pp[1024 + u] + pp[1536 + u]);
      float pre = tanhf(s + bu);
      float hzn = fmaf(DTz, pre - gu * hy - eu * hz, hz);
      hy = fmaf(DTz, hzn, hy);
      hz = hzn;
      hy_lds[u] = hy;
      if (u < 16 && t + 1 < Lz)
        ((float4*)x_lds)[u] = XG[((long)b * Lz + (t + 1)) * 16 + u];
    }
    __syncthreads();
    {
      float4 acc0 = make_float4(0.f,0.f,0.f,0.f), acc1 = make_float4(0.f,0.f,0.f,0.f);
      #pragma unroll 4
      for (int it = 0; it < 32; ++it) {
        int k4 = (it << 2) + ks;
        float4 hv = hy4[k4];
        float4 w0 = W4[(size_t)jj * 128 + k4];
        float4 w1 = W4[(size_t)(jj + 128) * 128 + k4];
        acc0.x = fmaf(hv.x, w0.x, acc0.x); acc0.y = fmaf(hv.y, w0.y, acc0.y);
        acc0.z = fmaf(hv.z, w0.z, acc0.z); acc0.w = fmaf(hv.w, w0.w, acc0.w);
        acc1.x = fmaf(hv.x, w1.x, acc1.x); acc1.y = fmaf(hv.y, w1.y, acc1.y);
        acc1.z = fmaf(hv.z, w1.z, acc1.z); acc1.w = fmaf(hv.w, w1.w, acc1.w);
      }
      float a0 = (acc0.x + acc0.y) + (acc0.z + acc0.w);
      float a1 = (acc1.x + acc1.y) + (acc1.z + acc1.w);
      a0 += __shfl_xor(a0, 1); a0 += __shfl_xor(a0, 2);
      a1 += __shfl_xor(a1, 1); a1 += __shfl_xor(a1, 2);
      if (ks == 0) { wx_lds[jj] = a0; wx_lds[jj + 128] = a1; }
    }
    __syncthreads();
    {
      float v = wx_lds[u & 255];
      zsum += (u < HALFz) ? cosf(v) : sinf(v);
    }
  }
  out[(long)b * Hz + u] = zsum * (0.0625f / 2048.f);
  out[(long)Bz * Hz + (long)b * Hz + u] = hy;
}

extern "C" void kernel_launch(void* const* d_in, const int* in_sizes, int n_in,
                              void* d_out, int out_size, void* d_ws, size_t ws_size,
                              hipStream_t stream) {
  const float* x    = (const float*)d_in[0];
  const float* x2h  = (const float*)d_in[1];
  const float* h2h  = (const float*)d_in[2];
  const float* bias = (const float*)d_in[3];
  const float* gam  = (const float*)d_in[4];
  const float* eps  = (const float*)d_in[5];
  const float* wrff = (const float*)d_in[6];
  float* out = (float*)d_out;

  // ws: X buffer 256KB (2 parity x 32 grp x 512 x u64) + Y buffer 256KB
  const size_t NEX = (size_t)2 * Bz * Hz;
  const size_t WS_NEED = 2 * NEX * sizeof(u64);         // 512 KB
  if (ws_size >= WS_NEED) {
    u64* Xb = (u64*)d_ws;
    u64* Yb = Xb + NEX;
    hipMemsetAsync(d_ws, 0, WS_NEED, stream);
    void* args[] = { (void*)&x, (void*)&x2h, (void*)&h2h, (void*)&bias,
                     (void*)&gam, (void*)&eps, (void*)&wrff,
                     (void*)&Xb, (void*)&Yb, (void*)&out };
    hipError_t e = hipLaunchCooperativeKernel((const void*)coesn_2c,
                                              dim3(NMEM * NPAIR), dim3(TPB),
                                              args, 0, stream);
    if (e == hipSuccess) return;
  }
  coesn_scan_fb<<<Bz, 512, 0, stream>>>(x, x2h, h2h, bias, gam, eps, wrff, out);
}

// Round 10
// 3620.851 us; speedup vs baseline: 1.9168x; 1.9168x over previous
//
#include <hip/hip_runtime.h>
#include <math.h>

#define Bz 32
#define Lz 2048
#define Iz 64
#define Hz 512
#define HALFz 256
#define DTz 0.05f
#define NMEM 8
#define NBLK 256
#define TPB 512

typedef unsigned long long u64;

__device__ __forceinline__ bool tagok(u64 v, unsigned tag) {
  u64 want = (u64)tag | ((u64)tag << 48);
  return ((v ^ want) & 0xFFFF00000000FFFFull) == 0ull;
}
__device__ __forceinline__ u64 packv(float f, unsigned tag) {
  return (u64)tag | ((u64)__float_as_uint(f) << 16) | ((u64)tag << 48);
}
__device__ __forceinline__ float unpackv(u64 v) {
  return __uint_as_float((unsigned)(v >> 16));
}

// sc0-only global access: bypass L1, read/write the XCD's L2.
__device__ __forceinline__ u64 load_sc0(const u64* p) {
  u64 r;
  asm volatile("global_load_dwordx2 %0, %1, off sc0\n\t"
               "s_waitcnt vmcnt(0)"
               : "=&v"(r) : "v"(p) : "memory");
  return r;
}
__device__ __forceinline__ void store_sc0(u64* p, u64 v) {
  asm volatile("global_store_dwordx2 %0, %1, off sc0"
               :: "v"(p), "v"(v) : "memory");
}

// ========== XCD-verified-grouping cooperative kernel (primary) ==========
// 256 blocks forced to 1/CU (96KB dynamic LDS) -> exactly 32 blocks per XCD.
// Startup: each block reads its physical XCD (s_getreg hwreg 20 = XCC_ID,
// HW-verified on MI355X), claims a per-XCD slot, crosses a one-shot grid
// barrier, then all blocks deterministically partition into 32 groups x 8
// members; full octets are XCD-LOCAL (leftovers, if any, form mixed groups
// that stay correct via the Y path). Group g computes batch b=g; member m
// owns H-cols [m*64,m*64+64) with weights register-resident (R6 layout).
// Exchange: tagged u64 {16 tag|32 payload|16 tag} dual-published to X (sc0 ->
// shared XCD L2: genuinely fast now that members share an XCD) and Y (agent
// atomic -> MALL safety net). Step tail ordered [Xst][spec-load][Yst] and the
// validation waits vmcnt(1) so the Y-store's MALL ack is NOT on the critical
// path. Retries alternate X (cheap) then Y (safe). 1 barrier/step.
// NOTE (R5 bug): rff_acc's shfl chain fully reduces wx into every lane of the
// 16-lane kseg group -> zc/zs complete per-lane; never re-reduce them.
__global__ __launch_bounds__(TPB, 1) void coesn_xg(
    const float* __restrict__ x, const float* __restrict__ x2h,
    const float* __restrict__ h2h, const float* __restrict__ bias,
    const float* __restrict__ gam, const float* __restrict__ eps,
    const float* __restrict__ W_rff, unsigned* __restrict__ regs,
    u64* __restrict__ Xb, u64* __restrict__ Yb, float* __restrict__ out) {
  extern __shared__ float lds_force[];          // occupancy limiter (unused)
  __shared__ __align__(16) float hyf[2][Hz];
  __shared__ __align__(16) float xbuf[2][Iz];
  __shared__ int sbm[2];                        // {batch, member} broadcast

  const int u = threadIdx.x;

  // ---- registration: verified-XCD group formation ----
  if (u == 0) {
    unsigned xcc = __builtin_amdgcn_s_getreg((31 << 11) | 20) & 7u;  // XCC_ID
    unsigned idx = __hip_atomic_fetch_add(regs + xcc, 1u, __ATOMIC_RELAXED,
                                          __HIP_MEMORY_SCOPE_AGENT);
    __hip_atomic_fetch_add(regs + 32, 1u, __ATOMIC_RELEASE,
                           __HIP_MEMORY_SCOPE_AGENT);
    unsigned v;
    do { v = __hip_atomic_load(regs + 32, __ATOMIC_ACQUIRE,
                               __HIP_MEMORY_SCOPE_AGENT); } while (v < NBLK);
    unsigned n[8], full[8], rem[8], totf = 0;
    for (int i = 0; i < 8; ++i) {
      n[i] = __hip_atomic_load(regs + i, __ATOMIC_RELAXED,
                               __HIP_MEMORY_SCOPE_AGENT);
      full[i] = n[i] >> 3; rem[i] = n[i] & 7; totf += full[i];
    }
    int gid, mem;
    if (idx < 8u * full[xcc]) {
      unsigned pf = 0;
      for (unsigned i = 0; i < xcc; ++i) pf += full[i];
      gid = (int)(pf + (idx >> 3)); mem = (int)(idx & 7u);
    } else {
      unsigned pr = 0;
      for (unsigned i = 0; i < xcc; ++i) pr += rem[i];
      unsigned rank = pr + (idx - 8u * full[xcc]);
      gid = (int)(totf + (rank >> 3)); mem = (int)(rank & 7u);
    }
    sbm[0] = gid; sbm[1] = mem;
  }
  __syncthreads();
  const int b = sbm[0];
  const int m = sbm[1];

  const int w  = u >> 6;          // wave id == owner-member of global col u
  const int l  = u & 63;
  const int c0 = m * 64;
  const int j  = ((l & 1) << 2) | (l & 2) | ((l >> 2) & 1);  // fold col map
  const int mycol = c0 + w * 8 + j;
  const int rloc = u >> 4, kseg = u & 15;

  // ---- weights into registers (one-time) ----
  float wreg[8][8];   // h2h[8l+r][c0+8w+c]
  {
    const float* hrow = h2h + (size_t)(8 * l) * Hz + c0 + 8 * w;
    #pragma unroll
    for (int r = 0; r < 8; ++r) {
      float4 v0 = *(const float4*)(hrow + (size_t)r * Hz);
      float4 v1 = *(const float4*)(hrow + (size_t)r * Hz + 4);
      wreg[r][0] = v0.x; wreg[r][1] = v0.y; wreg[r][2] = v0.z; wreg[r][3] = v0.w;
      wreg[r][4] = v1.x; wreg[r][5] = v1.y; wreg[r][6] = v1.z; wreg[r][7] = v1.w;
    }
  }
  float xreg[8];      // x2h[l][c0+8w+c]
  {
    float4 v0 = *(const float4*)(x2h + (size_t)l * Hz + c0 + 8 * w);
    float4 v1 = *(const float4*)(x2h + (size_t)l * Hz + c0 + 8 * w + 4);
    xreg[0] = v0.x; xreg[1] = v0.y; xreg[2] = v0.z; xreg[3] = v0.w;
    xreg[4] = v1.x; xreg[5] = v1.y; xreg[6] = v1.z; xreg[7] = v1.w;
  }
  float wr[32];       // W_rff[m*32+rloc][kseg*32 ..)
  {
    const float* wp = W_rff + (size_t)(m * 32 + rloc) * Hz + kseg * 32;
    #pragma unroll
    for (int i = 0; i < 32; ++i) wr[i] = wp[i];
  }

  const float bu = bias[mycol];
  const float gu = gam[mycol];
  const float eu = eps[mycol];
  float hy = 0.f, hz = 0.f, zc = 0.f, zs = 0.f;
  hyf[0][u] = 0.f;
  if (u < 16) ((float4*)xbuf[0])[u] = ((const float4*)(x + (size_t)b * Lz * Iz))[u];
  __syncthreads();

  auto rff_acc = [&](const float* hsrc) {
    float acc = 0.f;
    const float4* hp = (const float4*)hsrc;
    #pragma unroll
    for (int i = 0; i < 8; ++i) {
      int q = kseg * 8 + i;
      float4 h4 = hp[q ^ ((q >> 3) & 7)];
      acc = fmaf(h4.x, wr[4 * i], acc);
      acc = fmaf(h4.y, wr[4 * i + 1], acc);
      acc = fmaf(h4.z, wr[4 * i + 2], acc);
      acc = fmaf(h4.w, wr[4 * i + 3], acc);
    }
    acc += __shfl_xor(acc, 1); acc += __shfl_xor(acc, 2);
    acc += __shfl_xor(acc, 4); acc += __shfl_xor(acc, 8);
    float sv, cv;
    __sincosf(acc, &sv, &cv);
    zc += cv; zs += sv;   // complete per-lane across the 16-lane group
  };

  for (int t = 0; t < Lz; ++t) {
    const int cur = t & 1, nxt = cur ^ 1;

    // ---- x(t+1) prefetch ----
    if (u < 16 && t + 1 < Lz)
      ((float4*)xbuf[nxt])[u] =
          ((const float4*)(x + ((size_t)b * Lz + (t + 1)) * Iz))[u];

    // ---- matvec: lane covers K-rows [8l,8l+8) for cols c0+8w..+8 ----
    float hv[8];
    {
      const float4* hp = (const float4*)hyf[cur];
      int q0 = 2 * l, q1 = 2 * l + 1;
      float4 h0 = hp[q0 ^ ((q0 >> 3) & 7)];
      float4 h1 = hp[q1 ^ ((q1 >> 3) & 7)];
      hv[0] = h0.x; hv[1] = h0.y; hv[2] = h0.z; hv[3] = h0.w;
      hv[4] = h1.x; hv[5] = h1.y; hv[6] = h1.z; hv[7] = h1.w;
    }
    float a[8] = {0.f,0.f,0.f,0.f,0.f,0.f,0.f,0.f};
    #pragma unroll
    for (int r = 0; r < 8; ++r) {
      float h = hv[r];
      #pragma unroll
      for (int c = 0; c < 8; ++c) a[c] = fmaf(h, wreg[r][c], a[c]);
    }
    {
      float xv = xbuf[cur][l];
      #pragma unroll
      for (int c = 0; c < 8; ++c) a[c] = fmaf(xv, xreg[c], a[c]);
    }
    // ---- 10-shuffle fold ----
    #pragma unroll
    for (int i = 0; i < 4; ++i) {
      float snd = (l & 1) ? a[i] : a[i + 4];
      float rcv = __shfl_xor(snd, 1);
      a[i] = ((l & 1) ? a[i + 4] : a[i]) + rcv;
    }
    #pragma unroll
    for (int i = 0; i < 2; ++i) {
      float snd = (l & 2) ? a[i] : a[i + 2];
      float rcv = __shfl_xor(snd, 2);
      a[i] = ((l & 2) ? a[i + 2] : a[i]) + rcv;
    }
    float s;
    {
      float snd = (l & 4) ? a[0] : a[1];
      float rcv = __shfl_xor(snd, 4);
      s = ((l & 4) ? a[1] : a[0]) + rcv;
    }
    s += __shfl_xor(s, 8); s += __shfl_xor(s, 16); s += __shfl_xor(s, 32);

    // ---- state update ----
    s += bu;
    float e2 = __expf(s + s);
    float pre = 1.f - 2.f * __builtin_amdgcn_rcpf(e2 + 1.f);   // fast tanh
    float hzn = fmaf(DTz, pre - gu * hy - eu * hz, hz);
    hy = fmaf(DTz, hzn, hy);
    hz = hzn;

    const unsigned tag = (unsigned)(t + 1);
    u64* XA = Xb + ((size_t)nxt * Bz + b) * Hz;
    u64* YA = Yb + ((size_t)nxt * Bz + b) * Hz;

    // ---- publish X early (XCD L2 fast path) ----
    u64 pv = packv(hy, tag);
    if (l < 8) store_sc0(XA + mycol, pv);

    // ---- speculative remote poll issue ----
    u64 spec = 0;
    if (w != m)
      asm volatile("global_load_dwordx2 %0, %1, off sc0"
                   : "=&v"(spec) : "v"(XA + u) : "memory");

    // ---- publish Y (MALL safety net; younger than spec -> excluded by vmcnt(1)) ----
    if (l < 8) {
      __hip_atomic_store(YA + mycol, pv, __ATOMIC_RELAXED,
                         __HIP_MEMORY_SCOPE_AGENT);
      int q = mycol >> 2;
      hyf[nxt][((q ^ ((q >> 3) & 7)) << 2) | (mycol & 3)] = hy;   // local cols
    }

    // ---- RFF on hy(t) in the exchange shadow ----
    if (t > 0) rff_acc(hyf[cur]);

    // ---- validate remote column: wait spec WITHOUT draining Y-store ack ----
    if (w != m) {
      asm volatile("s_waitcnt vmcnt(1)" : "+v"(spec) :: "memory");
      u64 v = spec;
      if (!tagok(v, tag)) {
        long it = 0;
        for (;;) {
          v = load_sc0(XA + u);
          if (tagok(v, tag)) break;
          if (it & 1) {
            v = __hip_atomic_load(YA + u, __ATOMIC_RELAXED,
                                  __HIP_MEMORY_SCOPE_AGENT);
            if (tagok(v, tag)) break;
          }
          if (++it > (1 << 20)) break;   // safety bail
        }
      }
      int q = u >> 2;
      hyf[nxt][((q ^ ((q >> 3) & 7)) << 2) | (u & 3)] = unpackv(v);
    }
    __syncthreads();
  }

  // final RFF term on hy(Lz) (loop covered hy(1)..hy(Lz-1)); Lz even -> [0]
  rff_acc(hyf[0]);

  if (l < 8) out[(size_t)Bz * Hz + (size_t)b * Hz + mycol] = hy;
  if (kseg == 0) {
    const float sc = 0.0625f / 2048.f;   // (1/sqrt(256)) / L
    out[(size_t)b * Hz + m * 32 + rloc] = zc * sc;
    out[(size_t)b * Hz + HALFz + m * 32 + rloc] = zs * sc;
  }
}

// ================= secondary: proven R6 kernel (3412us) =================
__global__ __launch_bounds__(TPB, 2) void coesn_x2(
    const float* __restrict__ x, const float* __restrict__ x2h,
    const float* __restrict__ h2h, const float* __restrict__ bias,
    const float* __restrict__ gam, const float* __restrict__ eps,
    const float* __restrict__ W_rff, u64* __restrict__ Xb,
    u64* __restrict__ Yb, float* __restrict__ out) {
  __shared__ __align__(16) float hyf[2][Hz];
  __shared__ __align__(16) float xb[2][Iz];

  const int b  = blockIdx.x & 31;
  const int m  = blockIdx.x >> 5;
  const int u  = threadIdx.x;
  const int w  = u >> 6;
  const int l  = u & 63;
  const int c0 = m * 64;
  const int j  = ((l & 1) << 2) | (l & 2) | ((l >> 2) & 1);
  const int mycol = c0 + w * 8 + j;
  const int rloc = u >> 4, kseg = u & 15;

  float wreg[8][8];
  {
    const float* hrow = h2h + (size_t)(8 * l) * Hz + c0 + 8 * w;
    #pragma unroll
    for (int r = 0; r < 8; ++r) {
      float4 v0 = *(const float4*)(hrow + (size_t)r * Hz);
      float4 v1 = *(const float4*)(hrow + (size_t)r * Hz + 4);
      wreg[r][0] = v0.x; wreg[r][1] = v0.y; wreg[r][2] = v0.z; wreg[r][3] = v0.w;
      wreg[r][4] = v1.x; wreg[r][5] = v1.y; wreg[r][6] = v1.z; wreg[r][7] = v1.w;
    }
  }
  float xreg[8];
  {
    float4 v0 = *(const float4*)(x2h + (size_t)l * Hz + c0 + 8 * w);
    float4 v1 = *(const float4*)(x2h + (size_t)l * Hz + c0 + 8 * w + 4);
    xreg[0] = v0.x; xreg[1] = v0.y; xreg[2] = v0.z; xreg[3] = v0.w;
    xreg[4] = v1.x; xreg[5] = v1.y; xreg[6] = v1.z; xreg[7] = v1.w;
  }
  float wr[32];
  {
    const float* wp = W_rff + (size_t)(m * 32 + rloc) * Hz + kseg * 32;
    #pragma unroll
    for (int i = 0; i < 32; ++i) wr[i] = wp[i];
  }

  const float bu = bias[mycol];
  const float gu = gam[mycol];
  const float eu = eps[mycol];
  float hy = 0.f, hz = 0.f, zc = 0.f, zs = 0.f;
  hyf[0][u] = 0.f;
  if (u < 16) ((float4*)xb[0])[u] = ((const float4*)(x + (size_t)b * Lz * Iz))[u];
  __syncthreads();

  auto rff_acc = [&](const float* hsrc) {
    float acc = 0.f;
    const float4* hp = (const float4*)hsrc;
    #pragma unroll
    for (int i = 0; i < 8; ++i) {
      int q = kseg * 8 + i;
      float4 h4 = hp[q ^ ((q >> 3) & 7)];
      acc = fmaf(h4.x, wr[4 * i], acc);
      acc = fmaf(h4.y, wr[4 * i + 1], acc);
      acc = fmaf(h4.z, wr[4 * i + 2], acc);
      acc = fmaf(h4.w, wr[4 * i + 3], acc);
    }
    acc += __shfl_xor(acc, 1); acc += __shfl_xor(acc, 2);
    acc += __shfl_xor(acc, 4); acc += __shfl_xor(acc, 8);
    float sv, cv;
    __sincosf(acc, &sv, &cv);
    zc += cv; zs += sv;
  };

  for (int t = 0; t < Lz; ++t) {
    const int cur = t & 1, nxt = cur ^ 1;
    if (u < 16 && t + 1 < Lz)
      ((float4*)xb[nxt])[u] =
          ((const float4*)(x + ((size_t)b * Lz + (t + 1)) * Iz))[u];
    float hv[8];
    {
      const float4* hp = (const float4*)hyf[cur];
      int q0 = 2 * l, q1 = 2 * l + 1;
      float4 h0 = hp[q0 ^ ((q0 >> 3) & 7)];
      float4 h1 = hp[q1 ^ ((q1 >> 3) & 7)];
      hv[0] = h0.x; hv[1] = h0.y; hv[2] = h0.z; hv[3] = h0.w;
      hv[4] = h1.x; hv[5] = h1.y; hv[6] = h1.z; hv[7] = h1.w;
    }
    float a[8] = {0.f,0.f,0.f,0.f,0.f,0.f,0.f,0.f};
    #pragma unroll
    for (int r = 0; r < 8; ++r) {
      float h = hv[r];
      #pragma unroll
      for (int c = 0; c < 8; ++c) a[c] = fmaf(h, wreg[r][c], a[c]);
    }
    {
      float xv = xb[cur][l];
      #pragma unroll
      for (int c = 0; c < 8; ++c) a[c] = fmaf(xv, xreg[c], a[c]);
    }
    #pragma unroll
    for (int i = 0; i < 4; ++i) {
      float snd = (l & 1) ? a[i] : a[i + 4];
      float rcv = __shfl_xor(snd, 1);
      a[i] = ((l & 1) ? a[i + 4] : a[i]) + rcv;
    }
    #pragma unroll
    for (int i = 0; i < 2; ++i) {
      float snd = (l & 2) ? a[i] : a[i + 2];
      float rcv = __shfl_xor(snd, 2);
      a[i] = ((l & 2) ? a[i + 2] : a[i]) + rcv;
    }
    float s;
    {
      float snd = (l & 4) ? a[0] : a[1];
      float rcv = __shfl_xor(snd, 4);
      s = ((l & 4) ? a[1] : a[0]) + rcv;
    }
    s += __shfl_xor(s, 8); s += __shfl_xor(s, 16); s += __shfl_xor(s, 32);

    s += bu;
    float e2 = __expf(s + s);
    float pre = 1.f - 2.f * __builtin_amdgcn_rcpf(e2 + 1.f);
    float hzn = fmaf(DTz, pre - gu * hy - eu * hz, hz);
    hy = fmaf(DTz, hzn, hy);
    hz = hzn;

    const unsigned tag = (unsigned)(t + 1);
    u64* XA = Xb + ((size_t)nxt * Bz + b) * Hz;
    u64* YA = Yb + ((size_t)nxt * Bz + b) * Hz;

    if (l < 8) {
      u64 pv = packv(hy, tag);
      *(volatile u64*)(XA + mycol) = pv;
      __hip_atomic_store(YA + mycol, pv, __ATOMIC_RELAXED,
                         __HIP_MEMORY_SCOPE_AGENT);
      int q = mycol >> 2;
      hyf[nxt][((q ^ ((q >> 3) & 7)) << 2) | (mycol & 3)] = hy;
    }
    if (t > 0) rff_acc(hyf[cur]);
    if (w != m) {
      u64 v; int it = 0;
      for (;;) {
        v = *(volatile const u64*)(XA + u);
        if (tagok(v, tag)) break;
        if (it >= 2) {
          v = __hip_atomic_load(YA + u, __ATOMIC_RELAXED,
                                __HIP_MEMORY_SCOPE_AGENT);
          if (tagok(v, tag)) break;
        }
        if (++it > (1 << 20)) break;
      }
      int q = u >> 2;
      hyf[nxt][((q ^ ((q >> 3) & 7)) << 2) | (u & 3)] = unpackv(v);
    }
    __syncthreads();
  }

  rff_acc(hyf[0]);
  if (l < 8) out[(size_t)Bz * Hz + (size_t)b * Hz + mycol] = hy;
  if (kseg == 0) {
    const float sc = 0.0625f / 2048.f;
    out[(size_t)b * Hz + m * 32 + rloc] = zc * sc;
    out[(size_t)b * Hz + HALFz + m * 32 + rloc] = zs * sc;
  }
}

// ================= tertiary: single-block-per-batch (proven R1) =================
#define FMA4(P, S, W) do { (P).x = fmaf((S), (W).x, (P).x); (P).y = fmaf((S), (W).y, (P).y); \
                           (P).z = fmaf((S), (W).z, (P).z); (P).w = fmaf((S), (W).w, (P).w); } while(0)

__global__ __launch_bounds__(512) void coesn_scan_fb(
    const float* __restrict__ x, const float* __restrict__ x2h,
    const float* __restrict__ h2h, const float* __restrict__ bias,
    const float* __restrict__ gam, const float* __restrict__ eps,
    const float* __restrict__ W_rff, float* __restrict__ out) {
  const int b = blockIdx.x;
  const int u = threadIdx.x;
  __shared__ __align__(16) float hy_lds[Hz];
  __shared__ __align__(16) float x_lds[Iz];
  __shared__ float4 part[4][128];
  __shared__ float wx_lds[HALFz];

  float hy = 0.f, hz = 0.f, zsum = 0.f;
  const float bu = bias[u];
  const float gu = gam[u];
  const float eu = eps[u];

  const int kq = u >> 7;
  const int g  = u & 127;
  const int jj = u >> 2;
  const int ks = u & 3;

  const float4* __restrict__ H4 = (const float4*)h2h;
  const float4* __restrict__ X2 = (const float4*)x2h;
  const float4* __restrict__ W4 = (const float4*)W_rff;
  const float4* __restrict__ XG = (const float4*)x;
  const float4* hy4 = (const float4*)hy_lds;

  hy_lds[u] = 0.f;
  if (u < 16) ((float4*)x_lds)[u] = XG[(long)b * Lz * 16 + u];
  __syncthreads();

  for (int t = 0; t < Lz; ++t) {
    float4 p = make_float4(0.f, 0.f, 0.f, 0.f);
    {
      const float4* hp = (const float4*)&hy_lds[kq << 7];
      #pragma unroll 8
      for (int k4 = 0; k4 < 32; ++k4) {
        float4 hv = hp[k4];
        const float4* wr2 = &H4[(size_t)((kq << 7) + (k4 << 2)) * 128 + g];
        float4 w0 = wr2[0]; float4 w1 = wr2[128]; float4 w2 = wr2[256]; float4 w3 = wr2[384];
        FMA4(p, hv.x, w0); FMA4(p, hv.y, w1); FMA4(p, hv.z, w2); FMA4(p, hv.w, w3);
      }
      const float4* xp = (const float4*)&x_lds[kq << 4];
      #pragma unroll
      for (int k4 = 0; k4 < 4; ++k4) {
        float4 xv = xp[k4];
        const float4* wr2 = &X2[(size_t)((kq << 4) + (k4 << 2)) * 128 + g];
        float4 w0 = wr2[0]; float4 w1 = wr2[128]; float4 w2 = wr2[256]; float4 w3 = wr2[384];
        FMA4(p, xv.x, w0); FMA4(p, xv.y, w1); FMA4(p, xv.z, w2); FMA4(p, xv.w, w3);
      }
    }
    part[kq][g] = p;
    __syncthreads();
    {
      const float* pp = (const float*)part;
      float s = (pp[u] + pp[512 + u]) + (pp[1024 + u] + pp[1536 + u]);
      float pre = tanhf(s + bu);
      float hzn = fmaf(DTz, pre - gu * hy - eu * hz, hz);
      hy = fmaf(DTz, hzn, hy);
      hz = hzn;
      hy_lds[u] = hy;
      if (u < 16 && t + 1 < Lz)
        ((float4*)x_lds)[u] = XG[((long)b * Lz + (t + 1)) * 16 + u];
    }
    __syncthreads();
    {
      float4 acc0 = make_float4(0.f,0.f,0.f,0.f), acc1 = make_float4(0.f,0.f,0.f,0.f);
      #pragma unroll 4
      for (int it = 0; it < 32; ++it) {
        int k4 = (it << 2) + ks;
        float4 hv = hy4[k4];
        float4 w0 = W4[(size_t)jj * 128 + k4];
        float4 w1 = W4[(size_t)(jj + 128) * 128 + k4];
        acc0.x = fmaf(hv.x, w0.x, acc0.x); acc0.y = fmaf(hv.y, w0.y, acc0.y);
        acc0.z = fmaf(hv.z, w0.z, acc0.z); acc0.w = fmaf(hv.w, w0.w, acc0.w);
        acc1.x = fmaf(hv.x, w1.x, acc1.x); acc1.y = fmaf(hv.y, w1.y, acc1.y);
        acc1.z = fmaf(hv.z, w1.z, acc1.z); acc1.w = fmaf(hv.w, w1.w, acc1.w);
      }
      float a0 = (acc0.x + acc0.y) + (acc0.z + acc0.w);
      float a1 = (acc1.x + acc1.y) + (acc1.z + acc1.w);
      a0 += __shfl_xor(a0, 1); a0 += __shfl_xor(a0, 2);
      a1 += __shfl_xor(a1, 1); a1 += __shfl_xor(a1, 2);
      if (ks == 0) { wx_lds[jj] = a0; wx_lds[jj + 128] = a1; }
    }
    __syncthreads();
    {
      float v = wx_lds[u & 255];
      zsum += (u < HALFz) ? cosf(v) : sinf(v);
    }
  }
  out[(long)b * Hz + u] = zsum * (0.0625f / 2048.f);
  out[(long)Bz * Hz + (long)b * Hz + u] = hy;
}

extern "C" void kernel_launch(void* const* d_in, const int* in_sizes, int n_in,
                              void* d_out, int out_size, void* d_ws, size_t ws_size,
                              hipStream_t stream) {
  const float* x    = (const float*)d_in[0];
  const float* x2h  = (const float*)d_in[1];
  const float* h2h  = (const float*)d_in[2];
  const float* bias = (const float*)d_in[3];
  const float* gam  = (const float*)d_in[4];
  const float* eps  = (const float*)d_in[5];
  const float* wrff = (const float*)d_in[6];
  float* out = (float*)d_out;

  // ws: [0,4096) registration (xcnt[8] + bar); [4096,+256K) X; [+256K] Y
  const size_t NEX = (size_t)2 * Bz * Hz;               // u64 per buffer
  const size_t WS_NEED = 4096 + 2 * NEX * sizeof(u64);  // 4KB + 512KB
  const unsigned DYN_LDS = 96 * 1024;                   // occupancy: 1 block/CU

  if (ws_size >= WS_NEED) {
    unsigned* regs = (unsigned*)d_ws;
    u64* Xb = (u64*)((char*)d_ws + 4096);
    u64* Yb = Xb + NEX;
    hipMemsetAsync(d_ws, 0, WS_NEED, stream);

    // primary: verified-XCD grouping
    hipError_t ea = hipFuncSetAttribute((const void*)coesn_xg,
                                        hipFuncAttributeMaxDynamicSharedMemorySize,
                                        (int)DYN_LDS);
    if (ea == hipSuccess) {
      void* args[] = { (void*)&x, (void*)&x2h, (void*)&h2h, (void*)&bias,
                       (void*)&gam, (void*)&eps, (void*)&wrff,
                       (void*)&regs, (void*)&Xb, (void*)&Yb, (void*)&out };
      hipError_t e = hipLaunchCooperativeKernel((const void*)coesn_xg,
                                                dim3(NBLK), dim3(TPB),
                                                args, DYN_LDS, stream);
      if (e == hipSuccess) return;
    }

    // secondary: proven R6 static-grouping kernel
    void* args2[] = { (void*)&x, (void*)&x2h, (void*)&h2h, (void*)&bias,
                      (void*)&gam, (void*)&eps, (void*)&wrff,
                      (void*)&Xb, (void*)&Yb, (void*)&out };
    hipError_t e2 = hipLaunchCooperativeKernel((const void*)coesn_x2,
                                               dim3(Bz * NMEM), dim3(TPB),
                                               args2, 0, stream);
    if (e2 == hipSuccess) return;
  }
  coesn_scan_fb<<<Bz, 512, 0, stream>>>(x, x2h, h2h, bias, gam, eps, wrff, out);
}